// Round 9
// baseline (161.178 us; speedup 1.0000x reference)
//
#include <hip/hip_runtime.h>

// inputs (256,128,64) f32, mask (256,128) i32, qparams (4,2,10) f32,
// W (4,256,10) f32, b (4,256) f32.
// out f32: outputs(256,128,256) ++ hx(128,256) ++ cx(128,256).
#define T_LEN 256
#define BATCH 128
#define NQ 10
#define HID 256
#define OUT_HX (T_LEN * BATCH * HID)
#define OUT_CX (OUT_HX + BATCH * HID)
#define ZSTRIDE 48          // z row: 4 gates x 12 (10 used, float4-aligned)
#define NCH 16              // chains per block
#define NCHP 17             // padded
#define SEG 32              // t-steps per scan segment
#define NSEG 8              // segments (SEG*NSEG = 256)

// ---------------------------------------------------------------------------
// K1: analytic circuit z for each (t,b,g) -> zg[(b*256+t)*48 + g*12 + w].
// DP validated (== exact statevector sim r3/r4; passing since r6).
// ---------------------------------------------------------------------------
__global__ __launch_bounds__(256) void zcalc_kernel(
    const float* __restrict__ x, const float* __restrict__ qp,
    float* __restrict__ zg)
{
  const int flat = blockIdx.x * 256 + threadIdx.x;   // (t*128+b)*4+g
  const int g = flat & 3, tb = flat >> 2;
  const int t = tb >> 7, b = tb & 127;

  float cphi[NQ], sphi[NQ], cth[NQ], sth[NQ];
#pragma unroll
  for (int k = 0; k < NQ; ++k) {
    float ang = x[tb * 64 + k] + qp[g * 20 + k];
    sphi[k] = __sinf(ang);  cphi[k] = __cosf(ang);
    float t1 = qp[g * 20 + 10 + k];
    sth[k] = __sinf(t1);    cth[k] = __cosf(t1);
  }
  float* zp = zg + (b * T_LEN + t) * ZSTRIDE + g * 12;
#pragma unroll
  for (int w = 0; w < NQ; ++w) {
    float vI, vZ, vY, vX; int js;
    if (w == NQ - 1) { vI = 0.f; vZ = cth[NQ-1]; vY = sth[NQ-1]; vX = 0.f; js = NQ - 2; }
    else             { vI = 1.f; vZ = 0.f; vY = 0.f; vX = 0.f; js = w; }
#pragma unroll
    for (int j = js; j >= 0; --j) {
      float nI = cth[j] * (cphi[j+1] * vZ - sphi[j+1] * vY);
      float nZ = cth[j] * vI;
      float nY = sth[j] * vX;
      float nX = -sth[j] * (sphi[j+1] * vZ + cphi[j+1] * vY);
      vI = nI; vZ = nZ; vY = nY; vX = nX;
    }
    zp[w] = vI + cphi[0] * vZ - sphi[0] * vY;
  }
}

// ---------------------------------------------------------------------------
// K2: t-parallel gates + parallel-scan recurrence + t-parallel epilogue.
// Block=(b, 16-chain group), 256 threads: tid = ch*16 + g*4 + tq.
// A: for each 64-t chunk: stage z, compute all gate dots t-parallel,
//    fold mask, write f' (g0), u'=m*i*gbar (g1 via shfl from g2), o' (g3).
// B: 128 threads = 16 chains x 8 segs: serial affine compose of 32 steps
//    (2 FMA/step), shfl_up Hillis-Steele over segs, re-walk writing c_t.
// C: h_t = o'_t * tanh(c_t), coalesced stores, hx/cx at t=255.
// ---------------------------------------------------------------------------
__global__ __launch_bounds__(256) void scan_kernel(
    const float* __restrict__ zg, const int* __restrict__ mask,
    const float* __restrict__ W, const float* __restrict__ bias,
    float* __restrict__ out)
{
  const int b   = blockIdx.x;          // 0..127
  const int hq  = blockIdx.y;          // 0..15
  const int tid = threadIdx.x;         // 0..255
  const int tq  = tid & 3;
  const int g   = (tid >> 2) & 3;
  const int ch  = tid >> 4;            // 0..15
  const int h   = hq * NCH + ch;

  __shared__ __align__(16) float zs[64][ZSTRIDE];  // 12 KB
  __shared__ float fb[T_LEN][NCHP];                // 17 KB
  __shared__ float ub[T_LEN][NCHP];                // 17 KB (becomes c_t)
  __shared__ float ob[T_LEN][NCHP];                // 17 KB
  __shared__ float mk[T_LEN];                      // 1 KB   => 64 KB total

  float Wreg[NQ];
#pragma unroll
  for (int n = 0; n < NQ; ++n) Wreg[n] = W[(g * HID + h) * NQ + n];
  const float bg = bias[g * HID + h];

  for (int t0 = tid; t0 < T_LEN; t0 += 256) mk[t0] = (float)mask[t0 * BATCH + b];

  // gate transform constants: v = a_c * sigma(-scale*pre) + bt_c
  const float scale_in = (g == 2) ? -2.f : -1.f;
  const float a_c  = (g == 2) ? 2.f : 1.f;
  const float bt_c = (g == 2) ? -1.f : 0.f;

  const float4* zsrc = (const float4*)(zg + b * T_LEN * ZSTRIDE);
  const int g12 = g * 12;

  // ---- phase A: all gates, t-parallel ----
  for (int c4 = 0; c4 < 4; ++c4) {
    {
      float4* dst = (float4*)&zs[0][0];
#pragma unroll
      for (int i = 0; i < 3; ++i)
        dst[i * 256 + tid] = zsrc[c4 * 64 * (ZSTRIDE / 4) + i * 256 + tid];
    }
    __syncthreads();
#pragma unroll
    for (int k = 0; k < 16; ++k) {
      const int tl = tq + 4 * k;          // 0..63
      const int t  = c4 * 64 + tl;
      float4 za = *(const float4*)&zs[tl][g12];
      float4 zb = *(const float4*)&zs[tl][g12 + 4];
      float2 zc = *(const float2*)&zs[tl][g12 + 8];
      float acc0 = fmaf(za.x, Wreg[0], bg);
      acc0 = fmaf(za.y, Wreg[1], acc0);
      acc0 = fmaf(za.z, Wreg[2], acc0);
      acc0 = fmaf(za.w, Wreg[3], acc0);
      acc0 = fmaf(zc.x, Wreg[8], acc0);
      float acc1 = zb.x * Wreg[4];
      acc1 = fmaf(zb.y, Wreg[5], acc1);
      acc1 = fmaf(zb.z, Wreg[6], acc1);
      acc1 = fmaf(zb.w, Wreg[7], acc1);
      acc1 = fmaf(zc.y, Wreg[9], acc1);
      float pre = acc0 + acc1;

      float e = __expf(scale_in * pre);
      float v = fmaf(a_c, __builtin_amdgcn_rcpf(1.f + e), bt_c);
      float partner = __shfl_xor(v, 12, 64);   // g1 <-> g2 (and g0 <-> g3)
      float m = mk[t], im = 1.f - m;
      if (g == 0) fb[t][ch] = fmaf(m, v, im);          // f'
      if (g == 1) ub[t][ch] = m * v * partner;         // m^2 * i * gbar
      if (g == 3) ob[t][ch] = fmaf(m, v, im);          // o'
    }
    __syncthreads();
  }

  // ---- phase B: segmented parallel scan of c_t = f'c + u' ----
  if (tid < NCH * NSEG) {
    const int sch = tid >> 3;           // chain 0..15
    const int s   = tid & 7;            // segment 0..7
    const int t0  = s * SEG;
    float A = 1.f, B = 0.f;
#pragma unroll
    for (int j = 0; j < SEG; ++j) {
      float a = fb[t0 + j][sch];
      float u = ub[t0 + j][sch];
      B = fmaf(a, B, u);
      A *= a;
    }
#pragma unroll
    for (int d = 1; d < NSEG; d <<= 1) {
      float Af = __shfl_up(A, d, 64);
      float Bf = __shfl_up(B, d, 64);
      if (s >= d) { B = fmaf(A, Bf, B); A *= Af; }
    }
    float cin = __shfl_up(B, 1, 64);
    if (s == 0) cin = 0.f;
    float c = cin;
#pragma unroll
    for (int j = 0; j < SEG; ++j) {
      const int t = t0 + j;
      c = fmaf(fb[t][sch], c, ub[t][sch]);
      ub[t][sch] = c;                   // overwrite u' with c_t
    }
  }
  __syncthreads();

  // ---- phase C: h_t = o' * tanh(c_t), stores ----
  float* outb = out + b * HID + hq * NCH;
#pragma unroll
  for (int i = 0; i < 16; ++i) {
    const int p  = i * 256 + tid;       // 4096 = 256 t x 16 ch
    const int t  = p >> 4;
    const int cc = p & 15;
    float cv = ub[t][cc];
    float ov = ob[t][cc];
    float e2 = __expf(-2.f * cv);
    float th = fmaf(2.f, __builtin_amdgcn_rcpf(1.f + e2), -1.f);
    float hv = ov * th;
    outb[t * (BATCH * HID) + cc] = hv;
    if (t == T_LEN - 1) {
      out[OUT_HX + b * HID + hq * NCH + cc] = hv;
      out[OUT_CX + b * HID + hq * NCH + cc] = cv;
    }
  }
}

extern "C" void kernel_launch(void* const* d_in, const int* in_sizes, int n_in,
                              void* d_out, int out_size, void* d_ws, size_t ws_size,
                              hipStream_t stream)
{
  // identify arrays by unique element counts (order-proof)
  int ii = 0, im = 1, iq = 2, iw = 3, ib = 4;
  for (int i = 0; i < n_in; ++i) {
    switch (in_sizes[i]) {
      case 2097152: ii = i; break;   // inputs (256,128,64)
      case 32768:   im = i; break;   // mask (256,128)
      case 80:      iq = i; break;   // qparams (4,2,10)
      case 10240:   iw = i; break;   // W (4,256,10)
      case 1024:    ib = i; break;   // b (4,256)
      default: break;
    }
  }
  const float* inputs  = (const float*)d_in[ii];
  const int*   mask    = (const int*)d_in[im];
  const float* qparams = (const float*)d_in[iq];
  const float* W       = (const float*)d_in[iw];
  const float* bias    = (const float*)d_in[ib];
  float*       out     = (float*)d_out;

  float* zg = (float*)d_ws;   // 128*256*48*4 = 6.3 MB

  zcalc_kernel<<<dim3(T_LEN * BATCH * 4 / 256), dim3(256), 0, stream>>>(
      inputs, qparams, zg);
  scan_kernel<<<dim3(BATCH, HID / NCH), dim3(256), 0, stream>>>(
      zg, mask, W, bias, out);
}

// Round 10
// 155.200 us; speedup vs baseline: 1.0385x; 1.0385x over previous
//
#include <hip/hip_runtime.h>

// inputs (256,128,64) f32, mask (256,128) i32, qparams (4,2,10) f32,
// W (4,256,10) f32, b (4,256) f32.
// out f32: outputs(256,128,256) ++ hx(128,256) ++ cx(128,256).
#define T_LEN 256
#define BATCH 128
#define NQ 10
#define HID 256
#define OUT_HX (T_LEN * BATCH * HID)
#define OUT_CX (OUT_HX + BATCH * HID)
#define ZSTRIDE 48          // z row: 4 gates x 12 (10 used, float4-aligned)
#define NCH 16              // chains per block
#define NCHP 17             // padded row length
#define SEG 32              // t-steps per scan segment
#define NSEG 8              // segments (SEG*NSEG = 256)

// Row swizzle for fb/ub/ob: kills the 32-row-stride bank degeneracy in
// phase B (t = s*32+j across lanes): bank = 8s+sch+17*(j>>2) -> 2-way (free).
__device__ __forceinline__ int swz(int t) { return ((t & 3) << 6) | (t >> 2); }

// ---------------------------------------------------------------------------
// K1: analytic circuit z for each (t,b,g) -> zg[(b*256+t)*48 + g*12 + w].
// DP validated (== exact statevector sim r3/r4; passing since r6).
// ---------------------------------------------------------------------------
__global__ __launch_bounds__(256) void zcalc_kernel(
    const float* __restrict__ x, const float* __restrict__ qp,
    float* __restrict__ zg)
{
  const int flat = blockIdx.x * 256 + threadIdx.x;   // (t*128+b)*4+g
  const int g = flat & 3, tb = flat >> 2;
  const int t = tb >> 7, b = tb & 127;

  float cphi[NQ], sphi[NQ], cth[NQ], sth[NQ];
#pragma unroll
  for (int k = 0; k < NQ; ++k) {
    float ang = x[tb * 64 + k] + qp[g * 20 + k];
    sphi[k] = __sinf(ang);  cphi[k] = __cosf(ang);
    float t1 = qp[g * 20 + 10 + k];
    sth[k] = __sinf(t1);    cth[k] = __cosf(t1);
  }
  float* zp = zg + (b * T_LEN + t) * ZSTRIDE + g * 12;
#pragma unroll
  for (int w = 0; w < NQ; ++w) {
    float vI, vZ, vY, vX; int js;
    if (w == NQ - 1) { vI = 0.f; vZ = cth[NQ-1]; vY = sth[NQ-1]; vX = 0.f; js = NQ - 2; }
    else             { vI = 1.f; vZ = 0.f; vY = 0.f; vX = 0.f; js = w; }
#pragma unroll
    for (int j = js; j >= 0; --j) {
      float nI = cth[j] * (cphi[j+1] * vZ - sphi[j+1] * vY);
      float nZ = cth[j] * vI;
      float nY = sth[j] * vX;
      float nX = -sth[j] * (sphi[j+1] * vZ + cphi[j+1] * vY);
      vI = nI; vZ = nZ; vY = nY; vX = nX;
    }
    zp[w] = vI + cphi[0] * vZ - sphi[0] * vY;
  }
}

// ---------------------------------------------------------------------------
// K2: t-parallel gates + segmented parallel scan + t-parallel epilogue.
// Block=(b, 16-chain group), 256 threads: tid = ch*16 + g*4 + tq.
// ---------------------------------------------------------------------------
__global__ __launch_bounds__(256) void scan_kernel(
    const float* __restrict__ zg, const int* __restrict__ mask,
    const float* __restrict__ W, const float* __restrict__ bias,
    float* __restrict__ out)
{
  const int b   = blockIdx.x;          // 0..127
  const int hq  = blockIdx.y;          // 0..15
  const int tid = threadIdx.x;         // 0..255
  const int tq  = tid & 3;
  const int g   = (tid >> 2) & 3;
  const int ch  = tid >> 4;            // 0..15
  const int h   = hq * NCH + ch;

  __shared__ __align__(16) float zs[64][ZSTRIDE];  // 12 KB
  __shared__ float fb[T_LEN][NCHP];                // 17 KB (swizzled rows)
  __shared__ float ub[T_LEN][NCHP];                // 17 KB (becomes c_t)
  __shared__ float ob[T_LEN][NCHP];                // 17 KB
  __shared__ float mk[T_LEN];                      // 1 KB   => 64 KB total

  float Wreg[NQ];
#pragma unroll
  for (int n = 0; n < NQ; ++n) Wreg[n] = W[(g * HID + h) * NQ + n];
  const float bg = bias[g * HID + h];

  for (int t0 = tid; t0 < T_LEN; t0 += 256) mk[t0] = (float)mask[t0 * BATCH + b];

  // gate transform constants: v = a_c * sigma(-scale*pre) + bt_c
  const float scale_in = (g == 2) ? -2.f : -1.f;
  const float a_c  = (g == 2) ? 2.f : 1.f;
  const float bt_c = (g == 2) ? -1.f : 0.f;

  const float4* zsrc = (const float4*)(zg + b * T_LEN * ZSTRIDE);
  const int g12 = g * 12;

  // ---- phase A: all gates, t-parallel ----
  for (int c4 = 0; c4 < 4; ++c4) {
    {
      float4* dst = (float4*)&zs[0][0];
#pragma unroll
      for (int i = 0; i < 3; ++i)
        dst[i * 256 + tid] = zsrc[c4 * 64 * (ZSTRIDE / 4) + i * 256 + tid];
    }
    __syncthreads();
#pragma unroll
    for (int k = 0; k < 16; ++k) {
      const int tl = tq + 4 * k;          // 0..63
      const int t  = c4 * 64 + tl;
      float4 za = *(const float4*)&zs[tl][g12];
      float4 zb = *(const float4*)&zs[tl][g12 + 4];
      float2 zc = *(const float2*)&zs[tl][g12 + 8];
      float acc0 = fmaf(za.x, Wreg[0], bg);
      acc0 = fmaf(za.y, Wreg[1], acc0);
      acc0 = fmaf(za.z, Wreg[2], acc0);
      acc0 = fmaf(za.w, Wreg[3], acc0);
      acc0 = fmaf(zc.x, Wreg[8], acc0);
      float acc1 = zb.x * Wreg[4];
      acc1 = fmaf(zb.y, Wreg[5], acc1);
      acc1 = fmaf(zb.z, Wreg[6], acc1);
      acc1 = fmaf(zb.w, Wreg[7], acc1);
      acc1 = fmaf(zc.y, Wreg[9], acc1);
      float pre = acc0 + acc1;

      float e = __expf(scale_in * pre);
      float v = fmaf(a_c, __builtin_amdgcn_rcpf(1.f + e), bt_c);
      float partner = __shfl_xor(v, 12, 64);   // g1 <-> g2 (and g0 <-> g3)
      float m = mk[t], im = 1.f - m;
      const int row = swz(t);
      if (g == 0) fb[row][ch] = fmaf(m, v, im);          // f'
      if (g == 1) ub[row][ch] = m * v * partner;         // m^2 * i * gbar
      if (g == 3) ob[row][ch] = fmaf(m, v, im);          // o'
    }
    __syncthreads();
  }

  // ---- phase B: segmented parallel scan of c_t = f'c + u' ----
  if (tid < NCH * NSEG) {
    const int sch = tid >> 3;           // chain 0..15
    const int s   = tid & 7;            // segment 0..7
    const int t0  = s * SEG;
    float A = 1.f, B = 0.f;
#pragma unroll
    for (int j = 0; j < SEG; ++j) {
      const int row = swz(t0 + j);
      float a = fb[row][sch];
      float u = ub[row][sch];
      B = fmaf(a, B, u);
      A *= a;
    }
#pragma unroll
    for (int d = 1; d < NSEG; d <<= 1) {
      float Af = __shfl_up(A, d, 64);
      float Bf = __shfl_up(B, d, 64);
      if (s >= d) { B = fmaf(A, Bf, B); A *= Af; }
    }
    float cin = __shfl_up(B, 1, 64);
    if (s == 0) cin = 0.f;
    float c = cin;
#pragma unroll
    for (int j = 0; j < SEG; ++j) {
      const int row = swz(t0 + j);
      c = fmaf(fb[row][sch], c, ub[row][sch]);
      ub[row][sch] = c;                 // overwrite u' with c_t
    }
  }
  __syncthreads();

  // ---- phase C: h_t = o' * tanh(c_t), coalesced 64B stores ----
  float* outb = out + b * HID + hq * NCH;
#pragma unroll
  for (int i = 0; i < 16; ++i) {
    const int u  = tid >> 4;            // 0..15
    const int cc = tid & 15;
    const int t  = 4 * u + (i & 3) + 64 * (i >> 2);
    const int row = swz(t);
    float cv = ub[row][cc];
    float ov = ob[row][cc];
    float e2 = __expf(-2.f * cv);
    float th = fmaf(2.f, __builtin_amdgcn_rcpf(1.f + e2), -1.f);
    float hv = ov * th;
    outb[t * (BATCH * HID) + cc] = hv;
    if (t == T_LEN - 1) {
      out[OUT_HX + b * HID + hq * NCH + cc] = hv;
      out[OUT_CX + b * HID + hq * NCH + cc] = cv;
    }
  }
}

extern "C" void kernel_launch(void* const* d_in, const int* in_sizes, int n_in,
                              void* d_out, int out_size, void* d_ws, size_t ws_size,
                              hipStream_t stream)
{
  // identify arrays by unique element counts (order-proof)
  int ii = 0, im = 1, iq = 2, iw = 3, ib = 4;
  for (int i = 0; i < n_in; ++i) {
    switch (in_sizes[i]) {
      case 2097152: ii = i; break;   // inputs (256,128,64)
      case 32768:   im = i; break;   // mask (256,128)
      case 80:      iq = i; break;   // qparams (4,2,10)
      case 10240:   iw = i; break;   // W (4,256,10)
      case 1024:    ib = i; break;   // b (4,256)
      default: break;
    }
  }
  const float* inputs  = (const float*)d_in[ii];
  const int*   mask    = (const int*)d_in[im];
  const float* qparams = (const float*)d_in[iq];
  const float* W       = (const float*)d_in[iw];
  const float* bias    = (const float*)d_in[ib];
  float*       out     = (float*)d_out;

  float* zg = (float*)d_ws;   // 128*256*48*4 = 6.3 MB

  zcalc_kernel<<<dim3(T_LEN * BATCH * 4 / 256), dim3(256), 0, stream>>>(
      inputs, qparams, zg);
  scan_kernel<<<dim3(BATCH, HID / NCH), dim3(256), 0, stream>>>(
      zg, mask, W, bias, out);
}